// Round 11
// baseline (196.384 us; speedup 1.0000x reference)
//
#include <hip/hip_runtime.h>

// input_: (B=64, 2*N=16384, 2, 2, 16) f32 ; diag1/2: (N=8192, 2, 2, 8) f32
// out: (B, N, 2, 2, 23) f32
//   out[b,n,i,j,:] = sum_k conv(x1[b,n,i,k,:], d1[n,k,j,:]) + (x2, d2)
//
// Round 11: barrier-free, LDS-free — structurally a copy kernel with FMAs.
// Evidence: R6/R7/R8 (LDS-tiled, barrier-phased) all plateau 88-93 us; R9/R10
// pipelining failed (register spills / __syncthreads vmcnt(0) drain). A copy
// kernel hits 6.3 TB/s with NO inter-wave sync; this kernel has none either:
// thread=(b,n,i,j), acc[23], per-segment loads, direct 92 B/lane stores
// (measured 1.19x write amplification in R4 — costs ~5 us, accepted).
// This is R5's decomposition WITHOUT the launch_bounds min-waves hint that
// forced VGPR=32 + catastrophic spill (R3/R5 lesson). Live set ~58 regs ->
// natural allocation should land <=64 (m69 cliff: 8 waves/SIMD).
#define BB 64
#define NN 8192
#define D2C 8
#define DOUT 23

// One segment: fixed (half, k, j). xp -> 16 floats x[b,n,i,k,:],
// dp -> 8 floats d[n,k,j,:]. acc[u+v] += x[u]*d[v].
__device__ __forceinline__ void seg(const float4* __restrict__ xp,
                                    const float4* __restrict__ dp,
                                    float* __restrict__ acc) {
    float4 xq0 = xp[0], xq1 = xp[1], xq2 = xp[2], xq3 = xp[3];
    float4 dq0 = dp[0], dq1 = dp[1];

    const float xv[16] = {xq0.x, xq0.y, xq0.z, xq0.w, xq1.x, xq1.y, xq1.z, xq1.w,
                          xq2.x, xq2.y, xq2.z, xq2.w, xq3.x, xq3.y, xq3.z, xq3.w};
    const float dv[D2C] = {dq0.x, dq0.y, dq0.z, dq0.w, dq1.x, dq1.y, dq1.z, dq1.w};

#pragma unroll
    for (int v = 0; v < D2C; ++v) {
        const float c = dv[v];
#pragma unroll
        for (int u = 0; u < 16; ++u) {
            acc[u + v] += xv[u] * c;
        }
    }
}

__global__ __launch_bounds__(256) void hstackdiag_kernel(
    const float* __restrict__ input,
    const float* __restrict__ diag1,
    const float* __restrict__ diag2,
    float* __restrict__ out) {
    const int t = blockIdx.x * blockDim.x + threadIdx.x;  // linear (b, n, i, j)
    const int j = t & 1;
    const int i = (t >> 1) & 1;
    const int n = (t >> 2) & (NN - 1);
    const int b = t >> 15;

    // x[b][n][i][k][u] (half 1): float4 offset b*2N*16 + n*16 + i*8 + k*4
    const float4* xh = (const float4*)input +
                       (size_t)b * (2 * NN) * 16 + (size_t)n * 16 + (size_t)i * 8;
    // d[n][k][j][v]: float4 offset n*8 + k*4 + j*2
    const float4* dh1 = (const float4*)diag1 + (size_t)n * 8 + (size_t)j * 2;
    const float4* dh2 = (const float4*)diag2 + (size_t)n * 8 + (size_t)j * 2;

    float acc[DOUT];
#pragma unroll
    for (int u = 0; u < DOUT; ++u) acc[u] = 0.0f;

    seg(xh + 0, dh1 + 0, acc);                    // half 1, k=0
    seg(xh + 4, dh1 + 4, acc);                    // half 1, k=1
    seg(xh + (size_t)NN * 16 + 0, dh2 + 0, acc);  // half 2, k=0
    seg(xh + (size_t)NN * 16 + 4, dh2 + 4, acc);  // half 2, k=1

    // out[b][n][i][j][:]: flat float offset t*23; 92 B/lane contiguous span.
    float* o = out + (size_t)t * DOUT;
#pragma unroll
    for (int q = 0; q < DOUT; ++q) {
        o[q] = acc[q];
    }
}

extern "C" void kernel_launch(void* const* d_in, const int* in_sizes, int n_in,
                              void* d_out, int out_size, void* d_ws, size_t ws_size,
                              hipStream_t stream) {
    const float* input = (const float*)d_in[0];
    const float* diag1 = (const float*)d_in[1];
    const float* diag2 = (const float*)d_in[2];
    float* out = (float*)d_out;

    const int total = BB * NN * 2 * 2;   // 2,097,152 threads, one per (b,n,i,j)
    const int block = 256;
    const int grid = total / block;      // 8192 blocks, exact
    hstackdiag_kernel<<<grid, block, 0, stream>>>(input, diag1, diag2, out);
}

// Round 12
// 90.775 us; speedup vs baseline: 2.1634x; 2.1634x over previous
//
#include <hip/hip_runtime.h>
#include <stdint.h>

// input_: (B=64, 2*N=16384, 2, 2, 16) f32 ; diag1/2: (N=8192, 2, 2, 8) f32
// out: (B, N, 2, 2, 23) f32
//   out[b,n,i,j,:] = sum_k conv(x1[b,n,i,k,:], d1[n,k,j,:]) + (x2, d2)
//
// Round 12: wave-autonomous. R11 proved scattered stores cost ~128 us of L2
// line-transactions (WRITE 346 MB) -> stores must be lane-contiguous via LDS.
// R6/R7/R8 (barrier-phased, coalesced) plateau at 88; the residual gap vs the
// ~71 us roofline is the collective __syncthreads vmcnt(0) drains. This cell:
// coalesced stores AND zero barriers. LDS is WAVE-PRIVATE (8 KB/wave): each
// wave gll-stages its own 16 units (x1+x2, zero staging VGPRs -> no R9 spill),
// one wave-local s_waitcnt vmcnt(0), computes, redistributes out through its
// region, stores 368 contiguous float4. All sync = within-wave data deps.
// Chunk-XOR swizzle on the gll GLOBAL source (linear LDS dest, rule 21) makes
// compute ds_read_b128 ~4-way instead of 32-way on bank groups.
#define BB 64
#define NN 8192
#define DOUT 23

typedef const __attribute__((address_space(1))) uint32_t* gas_u32p;
typedef __attribute__((address_space(3))) uint32_t* las_u32p;

// involution on 8-bit chunk index: XOR unit bits (4..7) into low-4
__device__ __forceinline__ int swz8(int F) { return F ^ ((F >> 4) & 15); }

__device__ __forceinline__ void half_acc(const float4* __restrict__ region,
                                         int base, int u16, int i,
                                         float4 k0a, float4 k0b,
                                         float4 k1a, float4 k1b,
                                         float* __restrict__ acc) {
#pragma unroll
    for (int k = 0; k < 2; ++k) {
        const float4 q0 = k ? k1a : k0a;
        const float4 q1 = k ? k1b : k0b;
        const float dv[8] = {q0.x, q0.y, q0.z, q0.w, q1.x, q1.y, q1.z, q1.w};
#pragma unroll
        for (int q = 0; q < 4; ++q) {
            const int F = u16 * 16 + i * 8 + k * 4 + q;
            const float4 xq = region[base + swz8(F)];
            const float xe[4] = {xq.x, xq.y, xq.z, xq.w};
#pragma unroll
            for (int e = 0; e < 4; ++e) {
#pragma unroll
                for (int v = 0; v < 8; ++v) {
                    acc[q * 4 + e + v] += xe[e] * dv[v];
                }
            }
        }
    }
}

__global__ __launch_bounds__(256) void hstackdiag_kernel(
    const float* __restrict__ input,
    const float* __restrict__ diag1,
    const float* __restrict__ diag2,
    float* __restrict__ out) {
    __shared__ float4 lds[2048];  // 32 KB = 4 waves x 512 float4 (wave-private)

    const int t = threadIdx.x;
    const int lane = t & 63;
    const int w = t >> 6;
    const int bx = blockIdx.x;
    const int b = bx >> 7;                     // 128 tiles per b
    const int n0w = (bx & 127) * 64 + w * 16;  // this wave's 16 units

    float4* region = lds + w * 512;            // [0,256)=x1, [256,512)=x2

    // ---- stage x1+x2 (16 KB) via global_load_lds: dest linear (wave-uniform
    // base + lane*16, m104), source pre-swizzled (m173 / rule 21) ----
    const float4* gb = (const float4*)input +
                       (size_t)b * (2 * NN) * 16 + (size_t)n0w * 16;
    const float4* gb2 = gb + (size_t)NN * 16;
#pragma unroll
    for (int r = 0; r < 4; ++r) {
        const int S = swz8(r * 64 + lane);
        __builtin_amdgcn_global_load_lds((gas_u32p)(const void*)(gb + S),
                                         (las_u32p)(void*)(region + r * 64),
                                         16, 0, 0);
    }
#pragma unroll
    for (int r = 0; r < 4; ++r) {
        const int S = swz8(r * 64 + lane);
        __builtin_amdgcn_global_load_lds((gas_u32p)(const void*)(gb2 + S),
                                         (las_u32p)(void*)(region + 256 + r * 64),
                                         16, 0, 0);
    }

    // ---- diag loads (L2-hot), overlap the gll wait ----
    const int u16 = lane >> 2;
    const int i = (lane >> 1) & 1;
    const int j = lane & 1;
    const int n = n0w + u16;
    const float4* dp1 = (const float4*)diag1 + (size_t)n * 8 + j * 2;
    const float4* dp2 = (const float4*)diag2 + (size_t)n * 8 + j * 2;
    const float4 d1k0a = dp1[0], d1k0b = dp1[1], d1k1a = dp1[4], d1k1b = dp1[5];
    const float4 d2k0a = dp2[0], d2k0b = dp2[1], d2k1a = dp2[4], d2k1b = dp2[5];

    // wave-local drain of the 8 gll (and d loads); NOT a workgroup barrier
    asm volatile("s_waitcnt vmcnt(0)" ::: "memory");

    float acc[DOUT];
#pragma unroll
    for (int u = 0; u < DOUT; ++u) acc[u] = 0.0f;

    half_acc(region, 0, u16, i, d1k0a, d1k0b, d1k1a, d1k1b, acc);    // half 1
    half_acc(region, 256, u16, i, d2k0a, d2k0b, d2k1a, d2k1b, acc);  // half 2

    // ---- redistribute through the wave-private region, then 368 contiguous
    // float4 stores (within-wave RAW on same LDS object -> compiler lgkmcnt) ----
    float* sf = (float*)region;
    const int c = i * 2 + j;
#pragma unroll
    for (int q = 0; q < DOUT; ++q) {
        sf[u16 * 92 + c * DOUT + q] = acc[q];
    }
    float4* gout = (float4*)(out + ((size_t)b * NN + n0w) * (4 * DOUT));
#pragma unroll
    for (int m = 0; m < 5; ++m) {
        gout[m * 64 + lane] = region[m * 64 + lane];
    }
    if (lane < 48) gout[320 + lane] = region[320 + lane];
}

extern "C" void kernel_launch(void* const* d_in, const int* in_sizes, int n_in,
                              void* d_out, int out_size, void* d_ws, size_t ws_size,
                              hipStream_t stream) {
    const float* input = (const float*)d_in[0];
    const float* diag1 = (const float*)d_in[1];
    const float* diag2 = (const float*)d_in[2];
    float* out = (float*)d_out;

    const int grid = BB * (NN / 64);   // 8192 blocks (64 units per block)
    hstackdiag_kernel<<<grid, 256, 0, stream>>>(input, diag1, diag2, out);
}

// Round 13
// 89.095 us; speedup vs baseline: 2.2042x; 1.0189x over previous
//
#include <hip/hip_runtime.h>

// input_: (B=64, 2*N=16384, 2, 2, 16) f32 ; diag1/2: (N=8192, 2, 2, 8) f32
// out: (B, N, 2, 2, 23) f32
//   out[b,n,i,j,:] = sum_k conv(x1[b,n,i,k,:], d1[n,k,j,:]) + (x2, d2)
//
// FINAL (champion, round 6; 87.9 us): block-tiled LDS design.
// Verdict from the full experiment matrix (R2-R12): the op is bound at
// ~5.1 TB/s effective mixed R/W (449 MB useful traffic -> ~88 us), 81% of
// the 6.3 TB/s pure-copy ceiling. Occupancy 11->84%, zero-barrier variants,
// gll double-buffering, and multi-tile pipelining all land 88-93 us.
// Structure: block = 64 (b,n) units; x1/x2 reg-staged to 32 KB LDS with
// coalesced float4 loads; XOR chunk swizzle (involution L = G ^ ((G>>3)&7))
// kills the 8-way bank-group conflict on compute reads; thread = (unit,i,j)
// keeps live set ~= acc(23)+x(16)+d(8); output staged through LDS for
// full-line coalesced stores (scattered 92 B/lane stores cost 2.2x, R11).
// NO launch_bounds min-waves hint: it makes the allocator spill (R3/R5/R9).
#define BB 64
#define NN 8192
#define TILE 64
#define DOUT 23

__global__ __launch_bounds__(256) void hstackdiag_kernel(
    const float* __restrict__ input,
    const float* __restrict__ diag1,
    const float* __restrict__ diag2,
    float* __restrict__ out) {
    __shared__ float4 sbuf[2048];  // 32 KB: x1 chunks [0,1024), x2 [1024,2048)

    const int t = threadIdx.x;
    const int bx = blockIdx.x;
    const int b = bx >> 7;              // 128 ntiles per b
    const int n0 = (bx & 127) * TILE;

    // ---- stage x1/x2 tiles (16 KB each) into LDS, swizzled ----
    // global tile is contiguous: 64 units x 64 floats = 1024 float4 chunks.
    const float4* g1 = (const float4*)input + ((size_t)b * (2 * NN) + n0) * 16;
    const float4* g2 = g1 + (size_t)NN * 16;

    float4 r1[4], r2[4];
#pragma unroll
    for (int r = 0; r < 4; ++r) r1[r] = g1[r * 256 + t];
#pragma unroll
    for (int r = 0; r < 4; ++r) r2[r] = g2[r * 256 + t];
#pragma unroll
    for (int r = 0; r < 4; ++r) {
        const int G = r * 256 + t;
        const int L = G ^ ((G >> 3) & 7);   // involution; bank-spreads columns
        sbuf[L] = r1[r];
    }
#pragma unroll
    for (int r = 0; r < 4; ++r) {
        const int G = r * 256 + t;
        const int L = G ^ ((G >> 3) & 7);
        sbuf[1024 + L] = r2[r];
    }
    __syncthreads();

    // ---- compute: thread = (unit, i, j) ----
    const int j = t & 1;
    const int i = (t >> 1) & 1;
    const int unit = t >> 2;
    const int n = n0 + unit;

    // d[n][k][j][v]: float4 index n*8 + k*4 + j*2
    const float4* dp1 = (const float4*)diag1 + (size_t)n * 8 + j * 2;
    const float4* dp2 = (const float4*)diag2 + (size_t)n * 8 + j * 2;

    float acc[DOUT];
#pragma unroll
    for (int u = 0; u < DOUT; ++u) acc[u] = 0.0f;

#pragma unroll
    for (int h = 0; h < 2; ++h) {
        const int sb = h * 1024;
        const float4* dp = (h == 0) ? dp1 : dp2;
#pragma unroll
        for (int k = 0; k < 2; ++k) {
            float4 dq0 = dp[k * 4 + 0];
            float4 dq1 = dp[k * 4 + 1];
            float dv[8] = {dq0.x, dq0.y, dq0.z, dq0.w,
                           dq1.x, dq1.y, dq1.z, dq1.w};

            float xv[16];
#pragma unroll
            for (int q = 0; q < 4; ++q) {
                const int Gc = unit * 16 + i * 8 + k * 4 + q;
                const int Lc = Gc ^ ((Gc >> 3) & 7);
                float4 xq = sbuf[sb + Lc];
                xv[q * 4 + 0] = xq.x;
                xv[q * 4 + 1] = xq.y;
                xv[q * 4 + 2] = xq.z;
                xv[q * 4 + 3] = xq.w;
            }
#pragma unroll
            for (int v = 0; v < 8; ++v) {
                const float c = dv[v];
#pragma unroll
                for (int u = 0; u < 16; ++u) {
                    acc[u + v] += xv[u] * c;
                }
            }
        }
    }

    // ---- output: stage tile in LDS, then fully-coalesced stores ----
    __syncthreads();  // done reading sbuf
    float* sout = (float*)sbuf;  // 64 units * 92 floats = 23552 B < 32 KB
#pragma unroll
    for (int q = 0; q < DOUT; ++q) {
        sout[t * DOUT + q] = acc[q];  // bank = (23t+q)%32: 2 lanes/bank, free
    }
    __syncthreads();
    float* gout = out + ((size_t)b * NN + n0) * (4 * DOUT);  // contiguous tile
#pragma unroll
    for (int r = 0; r < DOUT; ++r) {
        gout[r * 256 + t] = sout[r * 256 + t];  // 1 KB/wave-instr, full lines
    }
}

extern "C" void kernel_launch(void* const* d_in, const int* in_sizes, int n_in,
                              void* d_out, int out_size, void* d_ws, size_t ws_size,
                              hipStream_t stream) {
    const float* input = (const float*)d_in[0];
    const float* diag1 = (const float*)d_in[1];
    const float* diag2 = (const float*)d_in[2];
    float* out = (float*)d_out;

    const int grid = BB * (NN / TILE);   // 64 * 128 = 8192 blocks
    hstackdiag_kernel<<<grid, 256, 0, stream>>>(input, diag1, diag2, out);
}